// Round 5
// baseline (62.390 us; speedup 1.0000x reference)
//
#include <hip/hip_runtime.h>

// Forward-fill per row. One 512-thread block (8 waves) per row; each wave
// owns a 1024-element segment = 4 chunks of 256 (one f32x4/i32x4 per lane
// per chunk). All 8 global loads issue up front; W dies into 4-bit masks;
// A stays in registers across the barrier. Ballot+clz gives each lane its
// "last dry" source lane with a single bpermute per chunk-half.

typedef float f32x4 __attribute__((ext_vector_type(4)));
typedef int i32x4 __attribute__((ext_vector_type(4)));

constexpr int S_CONST = 8192;
constexpr int NWAVE = 8;
constexpr int SEGV = S_CONST / 4 / NWAVE;  // 256 vec4 per segment
constexpr int NC = 4;                      // chunks (256 elems) per segment

__global__ __launch_bounds__(512) void ffill_kernel(const float* __restrict__ A,
                                                    const int* __restrict__ W,
                                                    float* __restrict__ O,
                                                    int B) {
    const int row = blockIdx.x;
    const int wid = threadIdx.x >> 6;
    const int lane = threadIdx.x & 63;

    __shared__ float s_val[NWAVE];
    __shared__ int s_has[NWAVE];

    const size_t base = (size_t)row * (S_CONST / 4) + (size_t)wid * SEGV;
    const f32x4* __restrict__ Aseg = reinterpret_cast<const f32x4*>(A) + base;
    const i32x4* __restrict__ Wseg = reinterpret_cast<const i32x4*>(W) + base;
    f32x4* __restrict__ Oseg = reinterpret_cast<f32x4*>(O) + base;

    const unsigned long long below = ((unsigned long long)1 << lane) - 1ull;

    // ---- Load everything (8 back-to-back dwordx4 loads) ----
    f32x4 a[NC];
    i32x4 w[NC];
    #pragma unroll
    for (int c = 0; c < NC; ++c) a[c] = Aseg[c * 64 + lane];
    #pragma unroll
    for (int c = 0; c < NC; ++c) w[c] = Wseg[c * 64 + lane];

    // ---- Masks (W dies here) ----
    int d[NC];
    #pragma unroll
    for (int c = 0; c < NC; ++c) {
        int dd = 0;
        if (w[c].x == 0) dd |= 1;
        if (w[c].y == 0) dd |= 2;
        if (w[c].z == 0) dd |= 4;
        if (w[c].w == 0) dd |= 8;
        d[c] = dd;
    }
    if ((wid == 0) & (lane == 0)) d[0] |= 1;  // global element 0 always counts

    // ---- Per-chunk cross-lane summaries ----
    unsigned long long m[NC];
    float f[NC], g[NC];
    float segval = 0.0f;
    int seghas = 0;
    #pragma unroll
    for (int c = 0; c < NC; ++c) {
        float v = 0.0f;
        if (d[c] & 1) v = a[c].x;
        if (d[c] & 2) v = a[c].y;
        if (d[c] & 4) v = a[c].z;
        if (d[c] & 8) v = a[c].w;

        m[c] = __ballot(d[c] != 0);
        const unsigned long long p = m[c] & below;
        f[c] = __shfl(v, 63 - __clzll(p | 1ull));    // last dry among lanes < me
        g[c] = __shfl(v, 63 - __clzll(m[c] | 1ull)); // last dry in whole chunk

        if (m[c]) segval = g[c];
        seghas |= (m[c] != 0ull);
    }

    if (lane == 0) {
        s_val[wid] = segval;
        s_has[wid] = seghas;
    }
    __syncthreads();

    // seed = last dry value among preceding segments (segment 0 always has one)
    float seed = 0.0f;
    for (int j = wid - 1; j >= 0; --j) {
        if (s_has[j]) { seed = s_val[j]; break; }
    }

    // ---- Fill + store (no memory reads; A is in registers) ----
    float carry = seed;
    #pragma unroll
    for (int c = 0; c < NC; ++c) {
        const unsigned long long p = m[c] & below;
        float run = p ? f[c] : carry;
        carry = (m[c] != 0ull) ? g[c] : carry;

        f32x4 o;
        if (d[c] & 1) run = a[c].x;
        o.x = run;
        if (d[c] & 2) run = a[c].y;
        o.y = run;
        if (d[c] & 4) run = a[c].z;
        o.z = run;
        if (d[c] & 8) run = a[c].w;
        o.w = run;
        __builtin_nontemporal_store(o, &Oseg[c * 64 + lane]);
    }
}

extern "C" void kernel_launch(void* const* d_in, const int* in_sizes, int n_in,
                              void* d_out, int out_size, void* d_ws, size_t ws_size,
                              hipStream_t stream) {
    const float* A = (const float*)d_in[0];
    const int* W = (const int*)d_in[1];
    float* O = (float*)d_out;

    const int B = in_sizes[0] / S_CONST;  // rows

    hipLaunchKernelGGL(ffill_kernel, dim3(B), dim3(512), 0, stream, A, W, O, B);
}